// Round 5
// baseline (177.000 us; speedup 1.0000x reference)
//
#include <hip/hip_runtime.h>

// RNNAdder round 5 (= round-4 design, compile fix): B=4096, T=128, HID=64.
// 512 WGs x 128 thr. WG = 8 seqs (M=8; rows 8..15 of the 16x16 tile stay 0).
// 2 waves, N-split 2: wave w owns hidden cols w*32..w*32+31 (2 N-tiles).
// h stored PACKED per dword: low16 = f16(h) [RTZ], high16 = f16((h-hi)*2048).
//   -> one ds_read_b128 pair per K-tile serves both hi and lo channels
//      (deinterleaved with v_perm), one b32 write per produced value.
// Recurrence: C1 = hi@Whh, C2 = lo@Whh (4+4 MFMAs), x = C1 + C2/2048 + PP.
// PP lookup from TRANSPOSED PPT[n][cmb] (stride 101 dwords: bank = 5c+cmb,
// 16 distinct banks per 16-lane group -> conflict-free).
// Output projection alternates between the 2 waves ((t&1)==w), reusing the
// just-published slot after the single per-step barrier.

typedef _Float16 half8 __attribute__((ext_vector_type(8)));
typedef float floatx4 __attribute__((ext_vector_type(4)));
typedef int intx4 __attribute__((ext_vector_type(4)));

#define MFMA16(A, B, C) __builtin_amdgcn_mfma_f32_16x16x32_f16((A), (B), (C), 0, 0, 0)
#define PERMLO 0x05040100u
#define PERMHI 0x07060302u

__device__ __forceinline__ half8 mkh8(int a, int b, int c, int d) {
    intx4 v; v.x = a; v.y = b; v.z = c; v.w = d;
    return __builtin_bit_cast(half8, v);
}

// tanh(x) then pack (f16 hi | f16 residual*2048) into one dword.
__device__ __forceinline__ int tanh_pack(float x) {
    float e2 = __builtin_amdgcn_exp2f(x * 2.885390081777927f);
    float hv = 1.f - 2.f * __builtin_amdgcn_rcpf(e2 + 1.f);
    int p0 = __builtin_bit_cast(int, __builtin_amdgcn_cvt_pkrtz(hv, hv));
    _Float16 hh = __builtin_bit_cast(_Float16, (unsigned short)(p0 & 0xFFFF));
    float hif = (float)hh;                          // RTZ-quantized hi
    return __builtin_bit_cast(int,
        __builtin_amdgcn_cvt_pkrtz(hv, (hv - hif) * 2048.f));
}

__global__ __launch_bounds__(128)
void rnn_mfma5(const int* __restrict__ num1, const int* __restrict__ num2,
               const float* __restrict__ E, const float* __restrict__ Wxh,
               const float* __restrict__ Whh, const float* __restrict__ bias,
               const float* __restrict__ Wd, const float* __restrict__ bd,
               float* __restrict__ out)
{
    __shared__ __align__(16) float PPT[64 * 101 + 3];  // [n][cmb], stride 101
    __shared__ __align__(16) int   Hp[2][16][68];      // packed h, row=seq
    __shared__ int cmb4[256];                          // cmb bytes [t][m]

    const int tid  = threadIdx.x;
    const int w    = tid >> 6;       // wave: N-block (cols w*32..w*32+31)
    const int lane = tid & 63;
    const int c    = lane & 15;
    const int q    = lane >> 4;
    const int g    = blockIdx.x;     // group of 8 sequences

    // ---- stage 1: P1 (bias folded) / P2 in scratch overlaid on Hp ----
    float* P1 = (float*)&Hp[0][0][0];   // 640 floats
    float* P2 = P1 + 640;               // 640 floats (total 5120 B < 8704 B)
    for (int idx = tid; idx < 640; idx += 128) {
        int v = idx >> 6, jj = idx & 63;
        float s1 = bias[jj], s2 = 0.f;
        #pragma unroll
        for (int i = 0; i < 32; ++i) {
            float e = E[v * 32 + i];
            s1 = fmaf(e, Wxh[i * 64 + jj], s1);
            s2 = fmaf(e, Wxh[(32 + i) * 64 + jj], s2);
        }
        P1[idx] = s1; P2[idx] = s2;
    }
    __syncthreads();

    // ---- stage 2: transposed combined table PPT[n][v1*10+v2] ----
    for (int idx = tid; idx < 6400; idx += 128) {
        int n = idx & 63, cv = idx >> 6;
        PPT[n * 101 + cv] = P1[(cv / 10) * 64 + n] + P2[(cv % 10) * 64 + n];
    }
    __syncthreads();   // P1/P2 consumed; Hp reusable

    // ---- stage 3: zero both h slots; stage cmb bytes ----
    {
        int* hz = &Hp[0][0][0];
        for (int i = tid; i < 2176; i += 128) hz[i] = 0;
        unsigned char* c8 = (unsigned char*)cmb4;
        for (int idx = tid; idx < 1024; idx += 128) {
            int t = idx >> 3, m = idx & 7;
            int s = g * 8 + m;
            c8[t * 8 + m] = (unsigned char)(num1[s * 128 + t] * 10 + num2[s * 128 + t]);
        }
    }

    // ---- B-fragments from global (L2-cached; startup only) ----
    half8 Wf[2][2], Wdf[2];
    #pragma unroll
    for (int nt = 0; nt < 2; ++nt)
        #pragma unroll
        for (int kt = 0; kt < 2; ++kt)
            #pragma unroll
            for (int j = 0; j < 8; ++j) {
                int k = kt * 32 + q * 8 + j;
                Wf[nt][kt][j] = (_Float16)Whh[k * 64 + w * 32 + nt * 16 + c];
            }
    #pragma unroll
    for (int kt = 0; kt < 2; ++kt)
        #pragma unroll
        for (int j = 0; j < 8; ++j) {
            int k = kt * 32 + q * 8 + j;
            Wdf[kt][j] = (c < 10) ? (_Float16)Wd[k * 10 + c] : (_Float16)0.f;
        }
    float bdv = (c < 10) ? bd[c] : 0.f;
    __syncthreads();

    const int ppb0 = (w * 32 + c) * 101;
    const int ppb1 = (w * 32 + 16 + c) * 101;
    const floatx4 z4 = {0.f, 0.f, 0.f, 0.f};

    for (int t = 0; t < 128; ++t) {
        const int sp = (t + 1) & 1, sc = t & 1;

        // ---- A-fragments: packed dwords -> deinterleave hi/lo ----
        const int* src = &Hp[sp][c][q * 8];
        intx4 d0 = *(const intx4*)src;
        intx4 d1 = *(const intx4*)(src + 4);
        intx4 d2 = *(const intx4*)(src + 32);
        intx4 d3 = *(const intx4*)(src + 36);
        half8 Ah0 = mkh8(__builtin_amdgcn_perm(d0.y, d0.x, PERMLO),
                         __builtin_amdgcn_perm(d0.w, d0.z, PERMLO),
                         __builtin_amdgcn_perm(d1.y, d1.x, PERMLO),
                         __builtin_amdgcn_perm(d1.w, d1.z, PERMLO));
        half8 Al0 = mkh8(__builtin_amdgcn_perm(d0.y, d0.x, PERMHI),
                         __builtin_amdgcn_perm(d0.w, d0.z, PERMHI),
                         __builtin_amdgcn_perm(d1.y, d1.x, PERMHI),
                         __builtin_amdgcn_perm(d1.w, d1.z, PERMHI));
        half8 Ah1 = mkh8(__builtin_amdgcn_perm(d2.y, d2.x, PERMLO),
                         __builtin_amdgcn_perm(d2.w, d2.z, PERMLO),
                         __builtin_amdgcn_perm(d3.y, d3.x, PERMLO),
                         __builtin_amdgcn_perm(d3.w, d3.z, PERMLO));
        half8 Al1 = mkh8(__builtin_amdgcn_perm(d2.y, d2.x, PERMHI),
                         __builtin_amdgcn_perm(d2.w, d2.z, PERMHI),
                         __builtin_amdgcn_perm(d3.y, d3.x, PERMHI),
                         __builtin_amdgcn_perm(d3.w, d3.z, PERMHI));

        floatx4 C1a = MFMA16(Ah0, Wf[0][0], z4); C1a = MFMA16(Ah1, Wf[0][1], C1a);
        floatx4 C1b = MFMA16(Ah0, Wf[1][0], z4); C1b = MFMA16(Ah1, Wf[1][1], C1b);
        floatx4 C2a = MFMA16(Al0, Wf[0][0], z4); C2a = MFMA16(Al1, Wf[0][1], C2a);
        floatx4 C2b = MFMA16(Al0, Wf[1][0], z4); C2b = MFMA16(Al1, Wf[1][1], C2b);

        int cp = cmb4[t * 2 + (q & 1)];   // 4 cmb bytes for this quad's rows

        #pragma unroll
        for (int r = 0; r < 4; ++r) {
            int cv = (cp >> (8 * r)) & 0xFF;
            float ppa = PPT[ppb0 + cv];
            float ppb = PPT[ppb1 + cv];
            float xa = fmaf(C2a[r], (1.f / 2048.f), C1a[r]) + ppa;
            float xb = fmaf(C2b[r], (1.f / 2048.f), C1b[r]) + ppb;
            int pa = tanh_pack(xa);
            int pb = tanh_pack(xb);
            if (q < 2) {   // rows 8..15 stay zero forever
                Hp[sc][q * 4 + r][w * 32 + c]      = pa;
                Hp[sc][q * 4 + r][w * 32 + 16 + c] = pb;
            }
        }
        __syncthreads();

        // ---- output projection: wave (t&1) projects h(t) ----
        if ((t & 1) == w) {
            const int* pr = &Hp[sc][c][q * 8];
            intx4 e0 = *(const intx4*)pr;
            intx4 e1 = *(const intx4*)(pr + 4);
            intx4 e2 = *(const intx4*)(pr + 32);
            intx4 e3 = *(const intx4*)(pr + 36);
            half8 Ph0 = mkh8(__builtin_amdgcn_perm(e0.y, e0.x, PERMLO),
                             __builtin_amdgcn_perm(e0.w, e0.z, PERMLO),
                             __builtin_amdgcn_perm(e1.y, e1.x, PERMLO),
                             __builtin_amdgcn_perm(e1.w, e1.z, PERMLO));
            half8 Ph1 = mkh8(__builtin_amdgcn_perm(e2.y, e2.x, PERMLO),
                             __builtin_amdgcn_perm(e2.w, e2.z, PERMLO),
                             __builtin_amdgcn_perm(e3.y, e3.x, PERMLO),
                             __builtin_amdgcn_perm(e3.w, e3.z, PERMLO));
            floatx4 Cp = MFMA16(Ph0, Wdf[0], z4);
            Cp         = MFMA16(Ph1, Wdf[1], Cp);
            if (q < 2 && c < 10) {
                #pragma unroll
                for (int r = 0; r < 4; ++r)
                    out[((g * 8 + q * 4 + r) * 128 + t) * 10 + c] = Cp[r] + bdv;
            }
        }
    }
}

extern "C" void kernel_launch(void* const* d_in, const int* in_sizes, int n_in,
                              void* d_out, int out_size, void* d_ws, size_t ws_size,
                              hipStream_t stream) {
    const int*   num1 = (const int*)d_in[0];
    const int*   num2 = (const int*)d_in[1];
    const float* E    = (const float*)d_in[2];
    const float* Wxh  = (const float*)d_in[3];
    const float* Whh  = (const float*)d_in[4];
    const float* b    = (const float*)d_in[5];
    const float* Wd   = (const float*)d_in[6];
    const float* bd   = (const float*)d_in[7];
    float* out = (float*)d_out;
    rnn_mfma5<<<512, 128, 0, stream>>>(num1, num2, E, Wxh, Whh, b, Wd, bd, out);
}

// Round 6
// 161.882 us; speedup vs baseline: 1.0934x; 1.0934x over previous
//
#include <hip/hip_runtime.h>

// RNNAdder round 6: barrier-free wave-independent recurrence.
// B=4096, T=128, HID=64, VOCAB=10. 256 WGs x 128 thr = 512 waves; each wave
// owns M=8 sequences and ALL 64 hidden cols -> no cross-wave data flow, no
// __syncthreads in the t-loop (only same-wave LDS ordering via lgkmcnt).
// MFMA shape 32x32x16_f16: A[m=lane&31][k=(lane>>5)*8+j], B[k][n=lane&31],
// C col=lane&31, row=(reg&3)+8*(reg>>2)+4*(lane>>5). With M=8 only C regs
// 0..3 are real (rows r+4*(lane>>5) = 0..7) -> 8 real tanh values per lane.
// Recurrence: C = h @ Whh over K=64 as 4 K-tiles (two 2-chains Ca,Cb),
// x = Ca+Cb + PP[cmb][n]; h = tanh(x) stored plain f16 (no residual).
// A-reads exec-masked to l5<8 (garbage A rows only feed garbage C rows 8..31).
// Projection: 4 more MFMAs reusing the same A-frags with Wd B-frags.
// PPT transposed [n][cmb], stride 101 dwords: bank = 5*l5+cmb -> conflict-free.
// Hh row stride 72 halves (144 B): 16B-aligned b128 A-reads, bank-clean writes.

typedef _Float16 half8 __attribute__((ext_vector_type(8)));
typedef float floatx16 __attribute__((ext_vector_type(16)));

#define MFMA32(A, B, C) __builtin_amdgcn_mfma_f32_32x32x16_f16((A), (B), (C), 0, 0, 0)

__global__ __launch_bounds__(128)
void rnn_mfma6(const int* __restrict__ num1, const int* __restrict__ num2,
               const float* __restrict__ E, const float* __restrict__ Wxh,
               const float* __restrict__ Whh, const float* __restrict__ bias,
               const float* __restrict__ Wd, const float* __restrict__ bd,
               float* __restrict__ out)
{
    __shared__ float P1[640], P2[640];
    __shared__ float PPT[64 * 101 + 3];                 // [n][cmb], stride 101
    __shared__ __align__(16) _Float16 Hh[2][8][72];     // per-wave h, stride 72
    __shared__ __align__(4) unsigned char cmbB[2][1024]; // per-wave cmb bytes [t][m]

    const int tid  = threadIdx.x;
    const int w    = tid >> 6;       // wave in WG (independent)
    const int lane = tid & 63;
    const int l5   = lane & 31;
    const int h32  = lane >> 5;
    const int g    = blockIdx.x;
    const int s0   = g * 16 + w * 8; // first sequence of this wave

    // ---- stage 1: P1 (bias folded) / P2 ----
    for (int idx = tid; idx < 640; idx += 128) {
        int v = idx >> 6, j = idx & 63;
        float a = bias[j], b2 = 0.f;
        #pragma unroll
        for (int i = 0; i < 32; ++i) {
            float e = E[v * 32 + i];
            a  = fmaf(e, Wxh[i * 64 + j], a);
            b2 = fmaf(e, Wxh[(32 + i) * 64 + j], b2);
        }
        P1[idx] = a; P2[idx] = b2;
    }
    __syncthreads();

    // ---- stage 2: transposed PP table; zero h; stage cmb bytes ----
    for (int idx = tid; idx < 6400; idx += 128) {
        int n = idx & 63, cv = idx >> 6;
        PPT[n * 101 + cv] = P1[(cv / 10) * 64 + n] + P2[(cv % 10) * 64 + n];
    }
    {
        int* hz = (int*)&Hh[0][0][0];
        for (int i = tid; i < 576; i += 128) hz[i] = 0;
    }
    for (int idx = tid; idx < 2048; idx += 128) {
        int ww = idx >> 10, r = idx & 1023, t = r >> 3, m = r & 7;
        int s = g * 16 + ww * 8 + m;
        cmbB[ww][t * 8 + m] =
            (unsigned char)(num1[s * 128 + t] * 10 + num2[s * 128 + t]);
    }

    // ---- B-fragments from global (L2-cached, startup only) ----
    half8 Wf[4][2], Wdf[4];
    #pragma unroll
    for (int kt = 0; kt < 4; ++kt)
        #pragma unroll
        for (int j = 0; j < 8; ++j) {
            int k = kt * 16 + h32 * 8 + j;
            Wf[kt][0][j] = (_Float16)Whh[k * 64 + l5];
            Wf[kt][1][j] = (_Float16)Whh[k * 64 + 32 + l5];
            Wdf[kt][j]   = (l5 < 10) ? (_Float16)Wd[k * 10 + l5] : (_Float16)0.f;
        }
    float bdv = (l5 < 10) ? bd[l5] : 0.f;
    __syncthreads();   // last barrier: PPT/Hh/cmb ready

    const floatx16 z16 = {0.f,0.f,0.f,0.f,0.f,0.f,0.f,0.f,
                          0.f,0.f,0.f,0.f,0.f,0.f,0.f,0.f};

    for (int t = 0; t < 128; ++t) {
        // PP prefetch (independent of h — off the critical path)
        int cw = ((const int*)cmbB[w])[t * 2 + h32];  // 4 cmb bytes, m=4*h32..+3
        float pp[2][4];
        #pragma unroll
        for (int nt = 0; nt < 2; ++nt)
            #pragma unroll
            for (int r = 0; r < 4; ++r) {
                int cv = (cw >> (8 * r)) & 0xFF;
                pp[nt][r] = PPT[(nt * 32 + l5) * 101 + cv];
            }

        // A-fragments (h(t-1)): masked to the 16 lanes whose rows are real
        half8 Ak[4];
        if (l5 < 8) {
            #pragma unroll
            for (int kt = 0; kt < 4; ++kt)
                Ak[kt] = *(const half8*)&Hh[w][l5][kt * 16 + h32 * 8];
        }

        // recurrence + tanh + h-store
        #pragma unroll
        for (int nt = 0; nt < 2; ++nt) {
            floatx16 Ca = MFMA32(Ak[0], Wf[0][nt], z16);
            Ca          = MFMA32(Ak[1], Wf[1][nt], Ca);
            floatx16 Cb = MFMA32(Ak[2], Wf[2][nt], z16);
            Cb          = MFMA32(Ak[3], Wf[3][nt], Cb);
            #pragma unroll
            for (int r = 0; r < 4; ++r) {
                float x  = (Ca[r] + Cb[r]) + pp[nt][r];
                float e2 = __builtin_amdgcn_exp2f(x * 2.885390081777927f);
                float hv = 1.f - 2.f * __builtin_amdgcn_rcpf(e2 + 1.f);
                Hh[w][r + 4 * h32][nt * 32 + l5] = (_Float16)hv;
            }
        }

        // output projection: reuse A-frags (h(t-1))?? no — project h(t) next
        // iteration would lag; instead project h(t-1)'s successor directly:
        // we project h(t) by reusing the A-frags of the NEXT iteration; to keep
        // it simple and correct we project h(t-1)-derived logits... (see below)
        // -> We project h(t) at iteration t+1 is wrong for t=127. Simplest:
        //    read back h(t) A-frags here (cheap, masked) and project now.
        half8 Pk[4];
        if (l5 < 8) {
            #pragma unroll
            for (int kt = 0; kt < 4; ++kt)
                Pk[kt] = *(const half8*)&Hh[w][l5][kt * 16 + h32 * 8];
        }
        floatx16 Cp = MFMA32(Pk[0], Wdf[0], z16);
        Cp          = MFMA32(Pk[1], Wdf[1], Cp);
        Cp          = MFMA32(Pk[2], Wdf[2], Cp);
        Cp          = MFMA32(Pk[3], Wdf[3], Cp);
        if (l5 < 10) {
            #pragma unroll
            for (int r = 0; r < 4; ++r)
                out[((s0 + r + 4 * h32) * 128 + t) * 10 + l5] = Cp[r] + bdv;
        }
    }
}

extern "C" void kernel_launch(void* const* d_in, const int* in_sizes, int n_in,
                              void* d_out, int out_size, void* d_ws, size_t ws_size,
                              hipStream_t stream) {
    const int*   num1 = (const int*)d_in[0];
    const int*   num2 = (const int*)d_in[1];
    const float* E    = (const float*)d_in[2];
    const float* Wxh  = (const float*)d_in[3];
    const float* Whh  = (const float*)d_in[4];
    const float* b    = (const float*)d_in[5];
    const float* Wd   = (const float*)d_in[6];
    const float* bd   = (const float*)d_in[7];
    float* out = (float*)d_out;
    rnn_mfma6<<<256, 128, 0, stream>>>(num1, num2, E, Wxh, Whh, b, Wd, bd, out);
}